// Round 18
// baseline (109.901 us; speedup 1.0000x reference)
//
#include <hip/hip_runtime.h>
#include <hip/hip_bf16.h>

#define BB 2
#define SS 2048
#define HH 16
#define DD 64

#define LOG2E 1.4426950408889634f

typedef __bf16 bf16x8 __attribute__((ext_vector_type(8)));
typedef float f32x4 __attribute__((ext_vector_type(4)));
typedef float f32x16 __attribute__((ext_vector_type(16)));

__device__ __forceinline__ void gld16(const __hip_bfloat16* g, __hip_bfloat16* l) {
    __builtin_amdgcn_global_load_lds(
        (const __attribute__((address_space(1))) unsigned int*)g,
        (__attribute__((address_space(3))) unsigned int*)l, 16, 0, 0);
}

// split 8 f32 into bf16 hi + bf16 residual (3-term MFMA scheme)
__device__ __forceinline__ void split8(const float* v, bf16x8& h8, bf16x8& l8) {
#pragma unroll
    for (int i = 0; i < 8; ++i) {
        const float x = v[i];
        const __bf16 hb = (__bf16)x;
        h8[i] = hb;
        l8[i] = (__bf16)(x - (float)hb);
    }
}

// ---------------------------------------------------------------------------
// Kernel 1: MFMA-based Q/K/V projection + V transpose + Q pre-scaling.
// (unchanged from round 17)
// ---------------------------------------------------------------------------
__global__ __launch_bounds__(128) void proj_kernel(
    const float* __restrict__ xq, const float* __restrict__ xk,
    const float* __restrict__ xv,
    const float* __restrict__ Wq, const float* __restrict__ bq,
    const float* __restrict__ Wk, const float* __restrict__ bk,
    const float* __restrict__ Wv, const float* __restrict__ bv,
    const float* __restrict__ inv_scale_p,
    __hip_bfloat16* __restrict__ Qp, __hip_bfloat16* __restrict__ Kp,
    __hip_bfloat16* __restrict__ Vt)
{
    __shared__ __attribute__((aligned(16))) __hip_bfloat16 tl[2][64][72];

    const int tid = threadIdx.x;
    const int wave = tid >> 6;
    const int lane = tid & 63;
    const int ln31 = lane & 31;
    const int hi = lane >> 5;
    const int bh = blockIdx.x;
    const int b = bh >> 4, h = bh & 15;
    const int s0 = blockIdx.y * 128 + wave * 64;
    const float qscale = LOG2E / inv_scale_p[0];

    const float* xs[3] = {xq, xk, xv};
    const float* Ws[3] = {Wq, Wk, Wv};
    const float* Bs[3] = {bq, bk, bv};

#pragma unroll
    for (int m = 0; m < 3; ++m) {
        bf16x8 wh[2][4], wl[2][4];
        float biasv[2];
#pragma unroll
        for (int Nb = 0; Nb < 2; ++Nb) {
            const int e = Nb * 32 + ln31;
            biasv[Nb] = Bs[m][e];
            const float* wr = Ws[m] + e * 64 + hi * 8;
#pragma unroll
            for (int kc = 0; kc < 4; ++kc) {
                float v[8];
                const float4 a = *(const float4*)(wr + kc * 16);
                const float4 c = *(const float4*)(wr + kc * 16 + 4);
                v[0] = a.x; v[1] = a.y; v[2] = a.z; v[3] = a.w;
                v[4] = c.x; v[5] = c.y; v[6] = c.z; v[7] = c.w;
                split8(v, wh[Nb][kc], wl[Nb][kc]);
            }
        }
        const float scale = (m == 0) ? qscale : 1.0f;

#pragma unroll
        for (int Mb = 0; Mb < 2; ++Mb) {
            const int s = s0 + Mb * 32 + ln31;
            const float* xr = xs[m] + ((size_t)(b * SS + s) * HH + h) * DD + hi * 8;
            bf16x8 xh[4], xl[4];
#pragma unroll
            for (int kc = 0; kc < 4; ++kc) {
                float v[8];
                const float4 a = *(const float4*)(xr + kc * 16);
                const float4 c = *(const float4*)(xr + kc * 16 + 4);
                v[0] = a.x; v[1] = a.y; v[2] = a.z; v[3] = a.w;
                v[4] = c.x; v[5] = c.y; v[6] = c.z; v[7] = c.w;
                split8(v, xh[kc], xl[kc]);
            }

            f32x16 acc[2];
#pragma unroll
            for (int Nb = 0; Nb < 2; ++Nb)
#pragma unroll
                for (int r = 0; r < 16; ++r) acc[Nb][r] = biasv[Nb];

#pragma unroll
            for (int Nb = 0; Nb < 2; ++Nb)
#pragma unroll
                for (int kc = 0; kc < 4; ++kc) {
                    acc[Nb] = __builtin_amdgcn_mfma_f32_32x32x16_bf16(xh[kc], wh[Nb][kc], acc[Nb], 0, 0, 0);
                    acc[Nb] = __builtin_amdgcn_mfma_f32_32x32x16_bf16(xl[kc], wh[Nb][kc], acc[Nb], 0, 0, 0);
                    acc[Nb] = __builtin_amdgcn_mfma_f32_32x32x16_bf16(xh[kc], wl[Nb][kc], acc[Nb], 0, 0, 0);
                }

            if (m < 2) {
#pragma unroll
                for (int Nb = 0; Nb < 2; ++Nb)
#pragma unroll
                    for (int r = 0; r < 16; ++r) {
                        const int row = Mb * 32 + (r & 3) + 8 * (r >> 2) + 4 * hi;
                        tl[wave][row][Nb * 32 + ln31] =
                            __float2bfloat16(acc[Nb][r] * scale);
                    }
            } else {
#pragma unroll
                for (int Nb = 0; Nb < 2; ++Nb)
#pragma unroll
                    for (int r = 0; r < 16; ++r) {
                        const int srow = Mb * 32 + (r & 3) + 8 * (r >> 2) + 4 * hi;
                        tl[wave][Nb * 32 + ln31][srow] = __float2bfloat16(acc[Nb][r]);
                    }
            }
        }

        if (m < 2) {
            __hip_bfloat16* outp = (m == 0 ? Qp : Kp) + ((size_t)bh * SS + s0) * DD;
#pragma unroll
            for (int j = 0; j < 8; ++j) {
                const int row = j * 8 + (lane >> 3);
                const int col = (lane & 7) * 8;
                bf16x8 v = *(const bf16x8*)&tl[wave][row][col];
                *(bf16x8*)(outp + row * 64 + col) = v;
            }
        } else {
            __hip_bfloat16* vtp = Vt + (size_t)bh * DD * SS + s0;
#pragma unroll
            for (int j = 0; j < 8; ++j) {
                const int d = j * 8 + (lane >> 3);
                const int scol = (lane & 7) * 8;
                bf16x8 v = *(const bf16x8*)&tl[wave][d][scol];
                *(bf16x8*)(vtp + (size_t)d * SS + scol) = v;
            }
        }
    }
}

// ---------------------------------------------------------------------------
// Kernel 1b: mask -> q-major bf16 with log2e premul (pure streaming).
//   maskB[b][q][t] = bf16(mask[b][q][t] * LOG2E)
// grid = BB*SS*SS/2048 = 4096; block = 256; 8 elems/thread.
// ---------------------------------------------------------------------------
__global__ __launch_bounds__(256) void maskb_kernel(
    const float* __restrict__ mask, __hip_bfloat16* __restrict__ mb)
{
    const size_t i = ((size_t)blockIdx.x * 256 + threadIdx.x) * 8;
    const float4 a = *(const float4*)(mask + i);
    const float4 c = *(const float4*)(mask + i + 4);
    union { bf16x8 v; __hip_bfloat162 h[4]; } u;
    u.h[0] = __float22bfloat162_rn(make_float2(a.x * LOG2E, a.y * LOG2E));
    u.h[1] = __float22bfloat162_rn(make_float2(a.z * LOG2E, a.w * LOG2E));
    u.h[2] = __float22bfloat162_rn(make_float2(c.x * LOG2E, c.y * LOG2E));
    u.h[3] = __float22bfloat162_rn(make_float2(c.z * LOG2E, c.w * LOG2E));
    *(bf16x8*)(mb + i) = u.v;
}

// ---------------------------------------------------------------------------
// Kernel 2: flash attention.  K/V staged via global_load_lds (dbuf, 32 KB).
// Mask read DIRECT from global maskB (q-major bf16): 8x dwordx2 per
// wave-tile, register-prefetched one tile ahead; per-wave L1-line-exact.
// 32x32x16 MFMA, 32 q-rows/wave, QBLK=128, mask-sharing XCD remap.
// grid = 512 (2 blocks/CU); block = 256 (4 waves); 1 barrier/tile.
// ---------------------------------------------------------------------------
__global__ __launch_bounds__(256, 2) void attn_kernel(
    const __hip_bfloat16* __restrict__ Qp, const __hip_bfloat16* __restrict__ Kp,
    const __hip_bfloat16* __restrict__ Vt, const __hip_bfloat16* __restrict__ maskB,
    float* __restrict__ out)
{
    __shared__ __attribute__((aligned(16))) __hip_bfloat16 Kl[2][4096];
    __shared__ __attribute__((aligned(16))) __hip_bfloat16 Vl[2][4096];

    const int tid = threadIdx.x;
    const int lane = tid & 63;
    const int wave = tid >> 6;
    const int ln31 = lane & 31;
    const int hi = lane >> 5;

    // mask-sharing XCD remap: hw = (g%8) + 8h + 128(g/8), g = qt*2+b
    const int hw = blockIdx.x;
    const int x = hw & 127;
    const int h = x >> 3;
    const int g = ((hw >> 7) << 3) + (x & 7);
    const int qt = g >> 1;
    const int b = g & 1;
    const int bh = b * 16 + h;

    const __hip_bfloat16* Qb = Qp + (size_t)bh * SS * DD;
    const __hip_bfloat16* Kb = Kp + (size_t)bh * SS * DD;
    const __hip_bfloat16* Vtb = Vt + (size_t)bh * DD * SS;

    const int q0 = qt * 128 + wave * 32;
    // per-lane mask row base (q-major): row q = q0 + ln31
    const __hip_bfloat16* mqb = maskB + ((size_t)b * SS + (size_t)(q0 + ln31)) * SS;

    const int srow = lane >> 3;
    const int scol = ((lane & 7) ^ srow) * 8;
    const int rswz = (lane & 7) << 4;

    bf16x8 qf[4];
    {
        const __hip_bfloat16* qptr = Qb + (size_t)(q0 + ln31) * DD + hi * 8;
#pragma unroll
        for (int kc = 0; kc < 4; ++kc)
            qf[kc] = *reinterpret_cast<const bf16x8*>(qptr + kc * 16);
    }

    bf16x8 ones;
#pragma unroll
    for (int i = 0; i < 8; ++i) ones[i] = (__bf16)1.0f;

    f32x16 o[2];
    f32x16 lacc;
    float m_r = -1e30f;
#pragma unroll
    for (int r = 0; r < 16; ++r) { o[0][r] = 0.f; o[1][r] = 0.f; lacc[r] = 0.f; }

#define STAGE(bufi, t0s)                                                        \
    {                                                                           \
        _Pragma("unroll")                                                       \
        for (int cc = 0; cc < 2; ++cc) {                                        \
            const int c = wave * 2 + cc;                                        \
            const int row = c * 8 + srow;                                       \
            gld16(Kb + (size_t)((t0s) + row) * DD + scol, &Kl[bufi][c * 512]);  \
            gld16(Vtb + (size_t)row * SS + (t0s) + scol, &Vl[bufi][c * 512]);   \
        }                                                                       \
    }

// 8x dwordx2 mask loads for tile t0s: quad (nt,T) covers t = nt*32+T*8+4hi+{0..3}
#define LOADM(MR, t0s)                                                          \
    {                                                                           \
        _Pragma("unroll")                                                       \
        for (int nt = 0; nt < 2; ++nt)                                          \
            _Pragma("unroll")                                                   \
            for (int T = 0; T < 4; ++T)                                         \
                MR[nt * 4 + T] = *(const unsigned long long*)(                  \
                    mqb + (t0s) + nt * 32 + T * 8 + 4 * hi);                    \
    }

#define KFRAG(nt, kc) (*(const bf16x8*)((const char*)Kl[buf] +                  \
        (nt) * 4096 + ln31 * 128 + (((kc) * 32 + hi * 16) ^ rswz)))
#define VFRAG(dblk, kc) (*(const bf16x8*)((const char*)Vl[buf] +                \
        (dblk) * 4096 + ln31 * 128 + (((kc) * 32 + hi * 16) ^ rswz)))

    unsigned long long mrA[8], mrB[8];
    LOADM(mrA, 0);
    STAGE(0, 0);
    __syncthreads();

    int buf = 0;
    for (int t0 = 0; t0 < SS; t0 += 64) {
        const bool has_next = (t0 + 64 < SS);

        // ---- prefetch next tile's mask + stage next K/V ----
        if (has_next) {
            LOADM(mrB, t0 + 64);
            STAGE(buf ^ 1, t0 + 64);
        }

        // ---- unpack current mask regs -> C-init (already *log2e) ----
        // s[nt][4T+j] = f32 of bf16 at t = nt*32 + 8T + 4hi + j
        f32x16 s[2];
#pragma unroll
        for (int nt = 0; nt < 2; ++nt)
#pragma unroll
            for (int T = 0; T < 4; ++T) {
                const unsigned lo = (unsigned)mrA[nt * 4 + T];
                const unsigned hh = (unsigned)(mrA[nt * 4 + T] >> 32);
                s[nt][4 * T + 0] = __uint_as_float(lo << 16);
                s[nt][4 * T + 1] = __uint_as_float(lo & 0xFFFF0000u);
                s[nt][4 * T + 2] = __uint_as_float(hh << 16);
                s[nt][4 * T + 3] = __uint_as_float(hh & 0xFFFF0000u);
            }

        // ---- QK^T (swapped): C col=q(ln31), row=t=nt*32+(r&3)+8(r>>2)+4hi ----
        __builtin_amdgcn_s_setprio(1);
#pragma unroll
        for (int kc = 0; kc < 4; ++kc) {
            bf16x8 k0 = KFRAG(0, kc);
            bf16x8 k1 = KFRAG(1, kc);
            s[0] = __builtin_amdgcn_mfma_f32_32x32x16_bf16(k0, qf[kc], s[0], 0, 0, 0);
            s[1] = __builtin_amdgcn_mfma_f32_32x32x16_bf16(k1, qf[kc], s[1], 0, 0, 0);
        }
        __builtin_amdgcn_s_setprio(0);

        // ---- defer-max: lane-local max over 32 vals + wave vote ----
        float pmax = fmaxf(s[0][0], fmaxf(s[0][1], s[0][2]));
#pragma unroll
        for (int r = 3; r < 16; r += 3)
            pmax = fmaxf(pmax, fmaxf(s[0][r], fmaxf(s[0][(r + 1) & 15], s[0][(r + 2) & 15])));
#pragma unroll
        for (int r = 0; r < 16; r += 4)
            pmax = fmaxf(pmax, fmaxf(fmaxf(s[1][r], s[1][r + 1]), fmaxf(s[1][r + 2], s[1][r + 3])));

        if (!__all(pmax - m_r <= 11.5f)) {
            // slow path (rare): full row-max (half-exchange) + rescale state
            float mx = fmaxf(pmax, __shfl_xor(pmax, 32));
            const float mn = fmaxf(m_r, mx);
            const float alpha = exp2f(m_r - mn);
            m_r = mn;
#pragma unroll
            for (int r = 0; r < 16; ++r) {
                const float a = __shfl(alpha, (r & 3) + 8 * (r >> 2) + 4 * hi);
                o[0][r] *= a; o[1][r] *= a; lacc[r] *= a;
            }
        }

        // ---- P = exp2(s - m) in place ----
#pragma unroll
        for (int nt = 0; nt < 2; ++nt)
#pragma unroll
            for (int r = 0; r < 16; ++r)
                s[nt][r] = __builtin_amdgcn_exp2f(s[nt][r] - m_r);

        // ---- V fragments ----
        bf16x8 vfr[2][4];
#pragma unroll
        for (int dblk = 0; dblk < 2; ++dblk)
#pragma unroll
            for (int kc = 0; kc < 4; ++kc)
                vfr[dblk][kc] = VFRAG(dblk, kc);

        // ---- P -> PV A-fragments in-register (one shfl_xor(32) per pair) ----
        bf16x8 pfa[4];
#pragma unroll
        for (int nt = 0; nt < 2; ++nt) {
            unsigned c[8];
#pragma unroll
            for (int j = 0; j < 8; ++j) {
                union { __hip_bfloat162 hh; unsigned u; } cu;
                cu.hh = __float22bfloat162_rn(make_float2(s[nt][2 * j], s[nt][2 * j + 1]));
                c[j] = cu.u;
            }
#pragma unroll
            for (int half = 0; half < 2; ++half) {
                const unsigned c0 = c[half * 4 + 0], c1 = c[half * 4 + 1];
                const unsigned c2 = c[half * 4 + 2], c3 = c[half * 4 + 3];
                const unsigned X  = hi ? c0 : c2;
                const unsigned Y  = (unsigned)__shfl_xor((int)X, 32);
                const unsigned X2 = hi ? c1 : c3;
                const unsigned Y2 = (unsigned)__shfl_xor((int)X2, 32);
                union { bf16x8 v; unsigned w[4]; } pu;
                pu.w[0] = hi ? Y : c0;
                pu.w[1] = hi ? Y2 : c1;
                pu.w[2] = hi ? c2 : Y;
                pu.w[3] = hi ? c3 : Y2;
                pfa[nt * 2 + half] = pu.v;
            }
        }

        // ---- O += P @ V ; l += P @ ones ----
        __builtin_amdgcn_s_setprio(1);
#pragma unroll
        for (int kc = 0; kc < 4; ++kc) {
            lacc = __builtin_amdgcn_mfma_f32_32x32x16_bf16(pfa[kc], ones, lacc, 0, 0, 0);
            o[0] = __builtin_amdgcn_mfma_f32_32x32x16_bf16(pfa[kc], vfr[0][kc], o[0], 0, 0, 0);
            o[1] = __builtin_amdgcn_mfma_f32_32x32x16_bf16(pfa[kc], vfr[1][kc], o[1], 0, 0, 0);
        }
        __builtin_amdgcn_s_setprio(0);

        // ---- rotate mask regs ----
#pragma unroll
        for (int k = 0; k < 8; ++k) mrA[k] = mrB[k];

        __syncthreads();
        buf ^= 1;
    }

    // ---- epilogue: normalize and store [B,H,S,D] f32 ----
#pragma unroll
    for (int r = 0; r < 16; ++r) {
        const float inv_l = 1.0f / lacc[r];
        const int q = q0 + (r & 3) + 8 * (r >> 2) + 4 * hi;
        float* orow = out + ((size_t)bh * SS + q) * DD + ln31;
        orow[0]  = o[0][r] * inv_l;
        orow[32] = o[1][r] * inv_l;
    }
#undef STAGE
#undef LOADM
#undef KFRAG
#undef VFRAG
}

extern "C" void kernel_launch(void* const* d_in, const int* in_sizes, int n_in,
                              void* d_out, int out_size, void* d_ws, size_t ws_size,
                              hipStream_t stream) {
    const float* xq        = (const float*)d_in[0];
    const float* xk        = (const float*)d_in[1];
    const float* xv        = (const float*)d_in[2];
    const float* mask      = (const float*)d_in[3];
    const float* inv_scale = (const float*)d_in[4];
    const float* Wq        = (const float*)d_in[5];
    const float* bq        = (const float*)d_in[6];
    const float* Wk        = (const float*)d_in[7];
    const float* bk        = (const float*)d_in[8];
    const float* Wv        = (const float*)d_in[9];
    const float* bv        = (const float*)d_in[10];

    __hip_bfloat16* Qp = (__hip_bfloat16*)d_ws;
    __hip_bfloat16* Kp = Qp + (size_t)BB * HH * SS * DD;
    __hip_bfloat16* Vt = Kp + (size_t)BB * HH * SS * DD;
    __hip_bfloat16* maskB = Vt + (size_t)BB * HH * SS * DD;  // 16.8 MB bf16
    float* out = (float*)d_out;

    maskb_kernel<<<dim3(BB * SS * SS / 2048), dim3(256), 0, stream>>>(mask, maskB);

    proj_kernel<<<dim3(BB * HH, SS / 128), dim3(128), 0, stream>>>(
        xq, xk, xv, Wq, bq, Wk, bk, Wv, bv, inv_scale, Qp, Kp, Vt);

    attn_kernel<<<dim3(512), dim3(256), 0, stream>>>(
        Qp, Kp, Vt, maskB, out);
}

// Round 19
// 96.381 us; speedup vs baseline: 1.1403x; 1.1403x over previous
//
#include <hip/hip_runtime.h>
#include <hip/hip_bf16.h>

#define BB 2
#define SS 2048
#define HH 16
#define DD 64

#define LOG2E 1.4426950408889634f

typedef __bf16 bf16x8 __attribute__((ext_vector_type(8)));
typedef float f32x4 __attribute__((ext_vector_type(4)));
typedef float f32x16 __attribute__((ext_vector_type(16)));

__device__ __forceinline__ void gld16(const __hip_bfloat16* g, __hip_bfloat16* l) {
    __builtin_amdgcn_global_load_lds(
        (const __attribute__((address_space(1))) unsigned int*)g,
        (__attribute__((address_space(3))) unsigned int*)l, 16, 0, 0);
}

// split 8 f32 into bf16 hi + bf16 residual (3-term MFMA scheme)
__device__ __forceinline__ void split8(const float* v, bf16x8& h8, bf16x8& l8) {
#pragma unroll
    for (int i = 0; i < 8; ++i) {
        const float x = v[i];
        const __bf16 hb = (__bf16)x;
        h8[i] = hb;
        l8[i] = (__bf16)(x - (float)hb);
    }
}

// ---------------------------------------------------------------------------
// Kernel 1: MFMA-based Q/K/V projection + V transpose + Q pre-scaling.
// (unchanged from round 17)
// ---------------------------------------------------------------------------
__global__ __launch_bounds__(128) void proj_kernel(
    const float* __restrict__ xq, const float* __restrict__ xk,
    const float* __restrict__ xv,
    const float* __restrict__ Wq, const float* __restrict__ bq,
    const float* __restrict__ Wk, const float* __restrict__ bk,
    const float* __restrict__ Wv, const float* __restrict__ bv,
    const float* __restrict__ inv_scale_p,
    __hip_bfloat16* __restrict__ Qp, __hip_bfloat16* __restrict__ Kp,
    __hip_bfloat16* __restrict__ Vt)
{
    __shared__ __attribute__((aligned(16))) __hip_bfloat16 tl[2][64][72];

    const int tid = threadIdx.x;
    const int wave = tid >> 6;
    const int lane = tid & 63;
    const int ln31 = lane & 31;
    const int hi = lane >> 5;
    const int bh = blockIdx.x;
    const int b = bh >> 4, h = bh & 15;
    const int s0 = blockIdx.y * 128 + wave * 64;
    const float qscale = LOG2E / inv_scale_p[0];

    const float* xs[3] = {xq, xk, xv};
    const float* Ws[3] = {Wq, Wk, Wv};
    const float* Bs[3] = {bq, bk, bv};

#pragma unroll
    for (int m = 0; m < 3; ++m) {
        bf16x8 wh[2][4], wl[2][4];
        float biasv[2];
#pragma unroll
        for (int Nb = 0; Nb < 2; ++Nb) {
            const int e = Nb * 32 + ln31;
            biasv[Nb] = Bs[m][e];
            const float* wr = Ws[m] + e * 64 + hi * 8;
#pragma unroll
            for (int kc = 0; kc < 4; ++kc) {
                float v[8];
                const float4 a = *(const float4*)(wr + kc * 16);
                const float4 c = *(const float4*)(wr + kc * 16 + 4);
                v[0] = a.x; v[1] = a.y; v[2] = a.z; v[3] = a.w;
                v[4] = c.x; v[5] = c.y; v[6] = c.z; v[7] = c.w;
                split8(v, wh[Nb][kc], wl[Nb][kc]);
            }
        }
        const float scale = (m == 0) ? qscale : 1.0f;

#pragma unroll
        for (int Mb = 0; Mb < 2; ++Mb) {
            const int s = s0 + Mb * 32 + ln31;
            const float* xr = xs[m] + ((size_t)(b * SS + s) * HH + h) * DD + hi * 8;
            bf16x8 xh[4], xl[4];
#pragma unroll
            for (int kc = 0; kc < 4; ++kc) {
                float v[8];
                const float4 a = *(const float4*)(xr + kc * 16);
                const float4 c = *(const float4*)(xr + kc * 16 + 4);
                v[0] = a.x; v[1] = a.y; v[2] = a.z; v[3] = a.w;
                v[4] = c.x; v[5] = c.y; v[6] = c.z; v[7] = c.w;
                split8(v, xh[kc], xl[kc]);
            }

            f32x16 acc[2];
#pragma unroll
            for (int Nb = 0; Nb < 2; ++Nb)
#pragma unroll
                for (int r = 0; r < 16; ++r) acc[Nb][r] = biasv[Nb];

#pragma unroll
            for (int Nb = 0; Nb < 2; ++Nb)
#pragma unroll
                for (int kc = 0; kc < 4; ++kc) {
                    acc[Nb] = __builtin_amdgcn_mfma_f32_32x32x16_bf16(xh[kc], wh[Nb][kc], acc[Nb], 0, 0, 0);
                    acc[Nb] = __builtin_amdgcn_mfma_f32_32x32x16_bf16(xl[kc], wh[Nb][kc], acc[Nb], 0, 0, 0);
                    acc[Nb] = __builtin_amdgcn_mfma_f32_32x32x16_bf16(xh[kc], wl[Nb][kc], acc[Nb], 0, 0, 0);
                }

            if (m < 2) {
#pragma unroll
                for (int Nb = 0; Nb < 2; ++Nb)
#pragma unroll
                    for (int r = 0; r < 16; ++r) {
                        const int row = Mb * 32 + (r & 3) + 8 * (r >> 2) + 4 * hi;
                        tl[wave][row][Nb * 32 + ln31] =
                            __float2bfloat16(acc[Nb][r] * scale);
                    }
            } else {
#pragma unroll
                for (int Nb = 0; Nb < 2; ++Nb)
#pragma unroll
                    for (int r = 0; r < 16; ++r) {
                        const int srow = Mb * 32 + (r & 3) + 8 * (r >> 2) + 4 * hi;
                        tl[wave][Nb * 32 + ln31][srow] = __float2bfloat16(acc[Nb][r]);
                    }
            }
        }

        if (m < 2) {
            __hip_bfloat16* outp = (m == 0 ? Qp : Kp) + ((size_t)bh * SS + s0) * DD;
#pragma unroll
            for (int j = 0; j < 8; ++j) {
                const int row = j * 8 + (lane >> 3);
                const int col = (lane & 7) * 8;
                bf16x8 v = *(const bf16x8*)&tl[wave][row][col];
                *(bf16x8*)(outp + row * 64 + col) = v;
            }
        } else {
            __hip_bfloat16* vtp = Vt + (size_t)bh * DD * SS + s0;
#pragma unroll
            for (int j = 0; j < 8; ++j) {
                const int d = j * 8 + (lane >> 3);
                const int scol = (lane & 7) * 8;
                bf16x8 v = *(const bf16x8*)&tl[wave][d][scol];
                *(bf16x8*)(vtp + (size_t)d * SS + scol) = v;
            }
        }
    }
}

// ---------------------------------------------------------------------------
// Kernel 1b: mask -> FRAGMENT-ORDER bf16 with log2e premul.
// For block (b, qt 0..15, tile tt 0..31): 16KB tile where thread (wave,lane)'s
// 32 values sit contiguous at chunk (wave*64+lane)*64B, word w = nt*8+j holds
// bf16 pair for r=2j,2j+1 with t = tt*64 + nt*32 + (r&3)+8*(r>>2)+4*hi,
// q = qt*128 + wave*32 + (lane&31).
// grid = BB*16*32 = 1024; block = 256.
// ---------------------------------------------------------------------------
__global__ __launch_bounds__(256) void maskf_kernel(
    const float* __restrict__ mask, __hip_bfloat16* __restrict__ mf)
{
    __shared__ float tl[128][65];
    const int bid = blockIdx.x;
    const int b = bid >> 9;
    const int qt = (bid >> 5) & 15;
    const int tt = bid & 31;
    const int tid = threadIdx.x;

    // ---- stage 128q x 64t f32 tile, coalesced ----
    const float* src = mask + (size_t)b * SS * SS + (size_t)(qt * 128) * SS + tt * 64;
    const int r0 = tid >> 4;            // 0..15
    const int c0 = (tid & 15) * 4;      // 0..60
#pragma unroll
    for (int p = 0; p < 8; ++p) {
        const int r = p * 16 + r0;
        const float4 v = *(const float4*)&src[(size_t)r * SS + c0];
        tl[r][c0 + 0] = v.x; tl[r][c0 + 1] = v.y;
        tl[r][c0 + 2] = v.z; tl[r][c0 + 3] = v.w;
    }
    __syncthreads();

    const int wave = tid >> 6, lane = tid & 63;
    const int ln31 = lane & 31, hi = lane >> 5;
    const int q = wave * 32 + ln31;

    unsigned w[16];
#pragma unroll
    for (int nt = 0; nt < 2; ++nt)
#pragma unroll
        for (int j = 0; j < 8; ++j) {
            const int ra = 2 * j, rb = 2 * j + 1;
            const int ta = nt * 32 + (ra & 3) + 8 * (ra >> 2) + 4 * hi;
            const int tb = nt * 32 + (rb & 3) + 8 * (rb >> 2) + 4 * hi;
            union { __hip_bfloat162 hh; unsigned u; } cu;
            cu.hh = __float22bfloat162_rn(
                make_float2(tl[q][ta] * LOG2E, tl[q][tb] * LOG2E));
            w[nt * 8 + j] = cu.u;
        }

    __hip_bfloat16* dst = mf + (size_t)bid * 8192 + (size_t)(wave * 64 + lane) * 32;
#pragma unroll
    for (int j = 0; j < 4; ++j)
        *(uint4*)((char*)dst + j * 16) = *(uint4*)&w[j * 4];
}

// ---------------------------------------------------------------------------
// Kernel 2: flash attention.  K/V staged via global_load_lds (dbuf, 32 KB).
// Mask fragments read DIRECT from maskF: 4 coalesced b128 global loads per
// wave-tile (contiguous 4KB per wave), register-prefetched one tile ahead.
// Zero mask DS ops.  32x32x16 MFMA, 32 q-rows/wave, QBLK=128.
// grid = 512 (2 blocks/CU); block = 256 (4 waves); 1 barrier/tile.
// ---------------------------------------------------------------------------
__global__ __launch_bounds__(256, 2) void attn_kernel(
    const __hip_bfloat16* __restrict__ Qp, const __hip_bfloat16* __restrict__ Kp,
    const __hip_bfloat16* __restrict__ Vt, const __hip_bfloat16* __restrict__ maskF,
    float* __restrict__ out)
{
    __shared__ __attribute__((aligned(16))) __hip_bfloat16 Kl[2][4096];
    __shared__ __attribute__((aligned(16))) __hip_bfloat16 Vl[2][4096];

    const int tid = threadIdx.x;
    const int lane = tid & 63;
    const int wave = tid >> 6;
    const int ln31 = lane & 31;
    const int hi = lane >> 5;

    // mask-sharing XCD remap: hw = (g%8) + 8h + 128(g/8), g = qt*2+b
    const int hw = blockIdx.x;
    const int x = hw & 127;
    const int h = x >> 3;
    const int g = ((hw >> 7) << 3) + (x & 7);
    const int qt = g >> 1;
    const int b = g & 1;
    const int bh = b * 16 + h;

    const __hip_bfloat16* Qb = Qp + (size_t)bh * SS * DD;
    const __hip_bfloat16* Kb = Kp + (size_t)bh * SS * DD;
    const __hip_bfloat16* Vtb = Vt + (size_t)bh * DD * SS;
    // this thread's mask chunk base (tile 0): + tt*8192 per tile
    const __hip_bfloat16* mfb = maskF + (size_t)((b * 16 + qt) * 32) * 8192
                                      + (size_t)(wave * 64 + lane) * 32;

    const int q0 = qt * 128 + wave * 32;

    const int srow = lane >> 3;
    const int scol = ((lane & 7) ^ srow) * 8;
    const int rswz = (lane & 7) << 4;

    bf16x8 qf[4];
    {
        const __hip_bfloat16* qptr = Qb + (size_t)(q0 + ln31) * DD + hi * 8;
#pragma unroll
        for (int kc = 0; kc < 4; ++kc)
            qf[kc] = *reinterpret_cast<const bf16x8*>(qptr + kc * 16);
    }

    bf16x8 ones;
#pragma unroll
    for (int i = 0; i < 8; ++i) ones[i] = (__bf16)1.0f;

    f32x16 o[2];
    f32x16 lacc;
    float m_r = -1e30f;
#pragma unroll
    for (int r = 0; r < 16; ++r) { o[0][r] = 0.f; o[1][r] = 0.f; lacc[r] = 0.f; }

#define STAGE(bufi, t0s)                                                        \
    {                                                                           \
        _Pragma("unroll")                                                       \
        for (int cc = 0; cc < 2; ++cc) {                                        \
            const int c = wave * 2 + cc;                                        \
            const int row = c * 8 + srow;                                       \
            gld16(Kb + (size_t)((t0s) + row) * DD + scol, &Kl[bufi][c * 512]);  \
            gld16(Vtb + (size_t)row * SS + (t0s) + scol, &Vl[bufi][c * 512]);   \
        }                                                                       \
    }

// 4 coalesced b128 mask loads for tile t0s (wave reads contiguous 4KB)
#define LOADM(MR, t0s)                                                          \
    {                                                                           \
        const __hip_bfloat16* _mp = mfb + ((size_t)((t0s) >> 6)) * 8192;        \
        MR[0] = *(const bf16x8*)(_mp);                                          \
        MR[1] = *(const bf16x8*)(_mp + 8);                                      \
        MR[2] = *(const bf16x8*)(_mp + 16);                                     \
        MR[3] = *(const bf16x8*)(_mp + 24);                                     \
    }

#define KFRAG(nt, kc) (*(const bf16x8*)((const char*)Kl[buf] +                  \
        (nt) * 4096 + ln31 * 128 + (((kc) * 32 + hi * 16) ^ rswz)))
#define VFRAG(dblk, kc) (*(const bf16x8*)((const char*)Vl[buf] +                \
        (dblk) * 4096 + ln31 * 128 + (((kc) * 32 + hi * 16) ^ rswz)))

    bf16x8 mrA[4], mrB[4];
    LOADM(mrA, 0);
    STAGE(0, 0);
    __syncthreads();

    int buf = 0;
    for (int t0 = 0; t0 < SS; t0 += 64) {
        const bool has_next = (t0 + 64 < SS);

        // ---- prefetch next tile's mask + stage next K/V ----
        if (has_next) {
            LOADM(mrB, t0 + 64);
            STAGE(buf ^ 1, t0 + 64);
        }

        // ---- unpack fragment-order mask regs -> C-init (already *log2e) ----
        f32x16 s[2];
#pragma unroll
        for (int nt = 0; nt < 2; ++nt)
#pragma unroll
            for (int j2 = 0; j2 < 2; ++j2) {
                union { bf16x8 v; unsigned w[4]; } u;
                u.v = mrA[nt * 2 + j2];
#pragma unroll
                for (int k = 0; k < 4; ++k) {
                    const int j = j2 * 4 + k;
                    s[nt][2 * j]     = __uint_as_float(u.w[k] << 16);
                    s[nt][2 * j + 1] = __uint_as_float(u.w[k] & 0xFFFF0000u);
                }
            }

        // ---- QK^T (swapped): C col=q(ln31), row=t=nt*32+(r&3)+8(r>>2)+4hi ----
        __builtin_amdgcn_s_setprio(1);
#pragma unroll
        for (int kc = 0; kc < 4; ++kc) {
            bf16x8 k0 = KFRAG(0, kc);
            bf16x8 k1 = KFRAG(1, kc);
            s[0] = __builtin_amdgcn_mfma_f32_32x32x16_bf16(k0, qf[kc], s[0], 0, 0, 0);
            s[1] = __builtin_amdgcn_mfma_f32_32x32x16_bf16(k1, qf[kc], s[1], 0, 0, 0);
        }
        __builtin_amdgcn_s_setprio(0);

        // ---- defer-max: lane-local max over 32 vals + wave vote ----
        float pmax = fmaxf(s[0][0], fmaxf(s[0][1], s[0][2]));
#pragma unroll
        for (int r = 3; r < 16; r += 3)
            pmax = fmaxf(pmax, fmaxf(s[0][r], fmaxf(s[0][(r + 1) & 15], s[0][(r + 2) & 15])));
#pragma unroll
        for (int r = 0; r < 16; r += 4)
            pmax = fmaxf(pmax, fmaxf(fmaxf(s[1][r], s[1][r + 1]), fmaxf(s[1][r + 2], s[1][r + 3])));

        if (!__all(pmax - m_r <= 11.5f)) {
            // slow path (rare): full row-max (half-exchange) + rescale state
            float mx = fmaxf(pmax, __shfl_xor(pmax, 32));
            const float mn = fmaxf(m_r, mx);
            const float alpha = exp2f(m_r - mn);
            m_r = mn;
#pragma unroll
            for (int r = 0; r < 16; ++r) {
                const float a = __shfl(alpha, (r & 3) + 8 * (r >> 2) + 4 * hi);
                o[0][r] *= a; o[1][r] *= a; lacc[r] *= a;
            }
        }

        // ---- P = exp2(s - m) in place ----
#pragma unroll
        for (int nt = 0; nt < 2; ++nt)
#pragma unroll
            for (int r = 0; r < 16; ++r)
                s[nt][r] = __builtin_amdgcn_exp2f(s[nt][r] - m_r);

        // ---- V fragments ----
        bf16x8 vfr[2][4];
#pragma unroll
        for (int dblk = 0; dblk < 2; ++dblk)
#pragma unroll
            for (int kc = 0; kc < 4; ++kc)
                vfr[dblk][kc] = VFRAG(dblk, kc);

        // ---- P -> PV A-fragments in-register (one shfl_xor(32) per pair) ----
        bf16x8 pfa[4];
#pragma unroll
        for (int nt = 0; nt < 2; ++nt) {
            unsigned c[8];
#pragma unroll
            for (int j = 0; j < 8; ++j) {
                union { __hip_bfloat162 hh; unsigned u; } cu;
                cu.hh = __float22bfloat162_rn(make_float2(s[nt][2 * j], s[nt][2 * j + 1]));
                c[j] = cu.u;
            }
#pragma unroll
            for (int half = 0; half < 2; ++half) {
                const unsigned c0 = c[half * 4 + 0], c1 = c[half * 4 + 1];
                const unsigned c2 = c[half * 4 + 2], c3 = c[half * 4 + 3];
                const unsigned X  = hi ? c0 : c2;
                const unsigned Y  = (unsigned)__shfl_xor((int)X, 32);
                const unsigned X2 = hi ? c1 : c3;
                const unsigned Y2 = (unsigned)__shfl_xor((int)X2, 32);
                union { bf16x8 v; unsigned w[4]; } pu;
                pu.w[0] = hi ? Y : c0;
                pu.w[1] = hi ? Y2 : c1;
                pu.w[2] = hi ? c2 : Y;
                pu.w[3] = hi ? c3 : Y2;
                pfa[nt * 2 + half] = pu.v;
            }
        }

        // ---- O += P @ V ; l += P @ ones ----
        __builtin_amdgcn_s_setprio(1);
#pragma unroll
        for (int kc = 0; kc < 4; ++kc) {
            lacc = __builtin_amdgcn_mfma_f32_32x32x16_bf16(pfa[kc], ones, lacc, 0, 0, 0);
            o[0] = __builtin_amdgcn_mfma_f32_32x32x16_bf16(pfa[kc], vfr[0][kc], o[0], 0, 0, 0);
            o[1] = __builtin_amdgcn_mfma_f32_32x32x16_bf16(pfa[kc], vfr[1][kc], o[1], 0, 0, 0);
        }
        __builtin_amdgcn_s_setprio(0);

        // ---- rotate mask regs ----
#pragma unroll
        for (int k = 0; k < 4; ++k) mrA[k] = mrB[k];

        __syncthreads();
        buf ^= 1;
    }

    // ---- epilogue: normalize and store [B,H,S,D] f32 ----
#pragma unroll
    for (int r = 0; r < 16; ++r) {
        const float inv_l = 1.0f / lacc[r];
        const int q = q0 + (r & 3) + 8 * (r >> 2) + 4 * hi;
        float* orow = out + ((size_t)bh * SS + q) * DD + ln31;
        orow[0]  = o[0][r] * inv_l;
        orow[32] = o[1][r] * inv_l;
    }
#undef STAGE
#undef LOADM
#undef KFRAG
#undef VFRAG
}

extern "C" void kernel_launch(void* const* d_in, const int* in_sizes, int n_in,
                              void* d_out, int out_size, void* d_ws, size_t ws_size,
                              hipStream_t stream) {
    const float* xq        = (const float*)d_in[0];
    const float* xk        = (const float*)d_in[1];
    const float* xv        = (const float*)d_in[2];
    const float* mask      = (const float*)d_in[3];
    const float* inv_scale = (const float*)d_in[4];
    const float* Wq        = (const float*)d_in[5];
    const float* bq        = (const float*)d_in[6];
    const float* Wk        = (const float*)d_in[7];
    const float* bk        = (const float*)d_in[8];
    const float* Wv        = (const float*)d_in[9];
    const float* bv        = (const float*)d_in[10];

    __hip_bfloat16* Qp = (__hip_bfloat16*)d_ws;
    __hip_bfloat16* Kp = Qp + (size_t)BB * HH * SS * DD;
    __hip_bfloat16* Vt = Kp + (size_t)BB * HH * SS * DD;
    __hip_bfloat16* maskF = Vt + (size_t)BB * HH * SS * DD;  // 16.8 MB bf16
    float* out = (float*)d_out;

    maskf_kernel<<<dim3(BB * 16 * 32), dim3(256), 0, stream>>>(mask, maskF);

    proj_kernel<<<dim3(BB * HH, SS / 128), dim3(128), 0, stream>>>(
        xq, xk, xv, Wq, bq, Wk, bk, Wv, bv, inv_scale, Qp, Kp, Vt);

    attn_kernel<<<dim3(512), dim3(256), 0, stream>>>(
        Qp, Kp, Vt, maskF, out);
}